// Round 12
// baseline (114.674 us; speedup 1.0000x reference)
//
#include <hip/hip_runtime.h>
#include <math.h>

#define NB 16
#define NN 768
#define NT 48
#define ND 2048
#define NROW (NB*NN)                 // 12288
#define SCALE 0.02209708691207961f   // 1/sqrt(2048)
#define NEGBIG (-3.4028234663852886e38f)
#define TAU 1e-3f
#define NKS 8                         // K-split in k_R
#define KS (ND/NKS)                   // 256 per slice
#define RPB 8                         // rows per k_final block

typedef _Float16 f16;
typedef f16  f16x8 __attribute__((ext_vector_type(8)));
typedef f16  f16x4 __attribute__((ext_vector_type(4)));
typedef float f32x4 __attribute__((ext_vector_type(4)));

__device__ __forceinline__ void stage16(const void* g, void* l) {
    __builtin_amdgcn_global_load_lds(
        (const __attribute__((address_space(1))) unsigned int*)g,
        (__attribute__((address_space(3))) unsigned int*)l, 16, 0, 0);
}

// ---------------- kernel 1: task rms-norm -> task_n fp32 + t_hi/t_lo f16 ----------------
__global__ __launch_bounds__(256) void k_prep_task(const float* __restrict__ task,
                                                   float* __restrict__ task_n,
                                                   f16* __restrict__ t_hi,
                                                   f16* __restrict__ t_lo) {
    __shared__ float sred[8];
    const int row = blockIdx.x;                 // b*NT + t
    const float4* src = (const float4*)(task + (size_t)row * ND);
    const int tid = threadIdx.x;
    float4 v0 = src[tid];
    float4 v1 = src[tid + 256];
    float s = v0.x*v0.x + v0.y*v0.y + v0.z*v0.z + v0.w*v0.w
            + v1.x*v1.x + v1.y*v1.y + v1.z*v1.z + v1.w*v1.w;
    #pragma unroll
    for (int off = 32; off > 0; off >>= 1) s += __shfl_down(s, off, 64);
    if ((tid & 63) == 0) sred[tid >> 6] = s;
    __syncthreads();
    if (tid == 0)
        sred[4] = 1.0f / sqrtf((sred[0]+sred[1]+sred[2]+sred[3]) * (1.0f/ND) + 1e-6f);
    __syncthreads();
    const float inv = sred[4];
    const size_t o = (size_t)row * ND;
    f16x4 h0, l0, h1, l1;
    float4 n0, n1;
    #pragma unroll
    for (int e = 0; e < 4; e++) {
        float f0 = (&v0.x)[e] * inv, f1 = (&v1.x)[e] * inv;
        (&n0.x)[e] = f0; (&n1.x)[e] = f1;
        f16 a = (f16)f0; h0[e] = a; l0[e] = (f16)(f0 - (float)a);
        f16 c = (f16)f1; h1[e] = c; l1[e] = (f16)(f1 - (float)c);
    }
    *(float4*)&task_n[o + tid*4]          = n0;
    *(float4*)&task_n[o + (tid+256)*4]    = n1;
    *(f16x4*)&t_hi[o + tid*4]             = h0;
    *(f16x4*)&t_lo[o + tid*4]             = l0;
    *(f16x4*)&t_hi[o + (tid+256)*4]       = h1;
    *(f16x4*)&t_lo[o + (tid+256)*4]       = l1;
}

// ---------------- kernel 2: R-partials + sumsq (streams patches once, pipelined) ------
// grid (12 rt, NKS ks, 16 b) = 1536 blocks = 6/CU; KS=256 -> 4 steps.
__global__ __launch_bounds__(256) void k_R(const float* __restrict__ patches,
                                           const f16* __restrict__ t_hi,
                                           const f16* __restrict__ t_lo,
                                           float* __restrict__ Rpart,
                                           float* __restrict__ ssqpart) {
    __shared__ __align__(16) char Ah[64*128], Al[64*128];   // 8 KB each
    __shared__ __align__(16) char Bh[48*128], Bl[48*128];   // 6 KB each (28 KB total)
    const int rt = blockIdx.x, ks = blockIdx.y, b = blockIdx.z;
    const int tid = threadIdx.x, wid = tid >> 6, lane = tid & 63;
    const int q15 = lane & 15, g4 = lane >> 4;
    const int trow = tid >> 2, tq = tid & 3;   // A-load: row 0..63, quad pos
    const int lr = lane >> 3, lgch = (lane & 7) ^ lr;
    const int cxor = q15 & 7;

    const float* gP = patches + ((size_t)(b*NN + rt*64))*ND + ks*KS;
    const f16* gTh = t_hi + (size_t)b*NT*ND + ks*KS;
    const f16* gTl = t_lo + (size_t)b*NT*ND + ks*KS;

    f32x4 acc[3];
    #pragma unroll
    for (int j = 0; j < 3; j++) acc[j] = (f32x4){0.f,0.f,0.f,0.f};
    float ssq = 0.f;

    const float* aptr = gP + (size_t)trow*ND + tq*16;
    float4 va[4], vb[4];
    #pragma unroll
    for (int k = 0; k < 4; k++) va[k] = *(const float4*)(aptr + k*4);

    auto body = [&](float4 (&v)[4], float4 (&vn)[4], int kk, bool last) {
        #pragma unroll
        for (int t2 = 0; t2 < 2; t2++) {
            const int u = wid + 4*t2;
            if (u < 6) {
                stage16(gTh + (size_t)(u*8 + lr)*ND + kk + lgch*8, Bh + u*1024);
                stage16(gTl + (size_t)(u*8 + lr)*ND + kk + lgch*8, Bl + u*1024);
            }
        }
        __builtin_amdgcn_sched_barrier(0);   // pin issue order: B before A
        if (!last) {
            #pragma unroll
            for (int k = 0; k < 4; k++)
                vn[k] = *(const float4*)(aptr + kk + 64 + k*4);
        }
        __builtin_amdgcn_sched_barrier(0);
        float lssq = 0.f;
        f16x8 hi8[2], lo8[2];
        #pragma unroll
        for (int k = 0; k < 4; k++)
            #pragma unroll
            for (int e = 0; e < 4; e++) {
                const float f = (&v[k].x)[e];
                lssq += f*f;
                const f16 h = (f16)f;
                hi8[k>>1][(k&1)*4 + e] = h;
                lo8[k>>1][(k&1)*4 + e] = (f16)(f - (float)h);
            }
        lssq += __shfl_xor(lssq, 1, 64);
        lssq += __shfl_xor(lssq, 2, 64);
        if (tq == 0) ssq += lssq;
        const int rb = trow * 128;
        #pragma unroll
        for (int c = 0; c < 2; c++) {
            const int ch = (2*tq + c) ^ (trow & 7);
            *(f16x8*)(Ah + rb + ch*16) = hi8[c];
            *(f16x8*)(Al + rb + ch*16) = lo8[c];
        }
        __builtin_amdgcn_sched_barrier(0);
        if (last) asm volatile("s_waitcnt vmcnt(0)" ::: "memory");
        else      asm volatile("s_waitcnt vmcnt(4)" ::: "memory");
        asm volatile("s_waitcnt lgkmcnt(0)" ::: "memory");
        __builtin_amdgcn_s_barrier();
        __builtin_amdgcn_sched_barrier(0);
        #pragma unroll
        for (int ksub = 0; ksub < 2; ksub++) {
            const int chb = ((ksub*4 + g4) ^ cxor) << 4;
            const f16x8 a_h = *(const f16x8*)(Ah + (wid*16 + q15)*128 + chb);
            const f16x8 a_l = *(const f16x8*)(Al + (wid*16 + q15)*128 + chb);
            #pragma unroll
            for (int j = 0; j < 3; j++) {
                const f16x8 b_h = *(const f16x8*)(Bh + (j*16 + q15)*128 + chb);
                const f16x8 b_l = *(const f16x8*)(Bl + (j*16 + q15)*128 + chb);
                acc[j] = __builtin_amdgcn_mfma_f32_16x16x32_f16(a_h, b_h, acc[j], 0, 0, 0);
                acc[j] = __builtin_amdgcn_mfma_f32_16x16x32_f16(a_l, b_h, acc[j], 0, 0, 0);
                acc[j] = __builtin_amdgcn_mfma_f32_16x16x32_f16(a_h, b_l, acc[j], 0, 0, 0);
            }
        }
        asm volatile("" ::: "memory");
        __builtin_amdgcn_s_barrier();
        __builtin_amdgcn_sched_barrier(0);
    };

    // KS/64 = 4 steps, statically paired register double-buffer (rule #20)
    body(va, vb,   0, false);
    body(vb, va,  64, false);
    body(va, vb, 128, false);
    body(vb, va, 192, true);

    const int grow = b*NN + rt*64;
    #pragma unroll
    for (int j = 0; j < 3; j++)
        #pragma unroll
        for (int r = 0; r < 4; r++)
            Rpart[((size_t)ks*NROW + grow + wid*16 + g4*4 + r)*48 + j*16 + q15] = acc[j][r];
    if (tq == 0)
        ssqpart[(size_t)ks*NROW + grow + trow] = ssq;
}

// ---------------- kernel 3: combine -> pinv, w(=exp, unnormalized), W/G f16 hi-lo -----
// softmax normalization dropped: argmax and rescore are invariant to the positive
// per-row 1/sum factor.
__global__ __launch_bounds__(256) void k_combine(const float* __restrict__ Rpart,
                                                 const float* __restrict__ ssqpart,
                                                 const int* __restrict__ mask,
                                                 float* __restrict__ w,
                                                 float* __restrict__ pinv,
                                                 f16* __restrict__ Whi,
                                                 f16* __restrict__ Wlo,
                                                 f16* __restrict__ Ghi,
                                                 f16* __restrict__ Glo) {
    const int r = blockIdx.x * 256 + threadIdx.x;   // 0..12287
    const int b = r / NN;
    float ss = 0.f;
    #pragma unroll
    for (int ks = 0; ks < NKS; ks++) ss += ssqpart[(size_t)ks*NROW + r];
    const float pv = 1.0f / sqrtf(ss * (1.0f/ND) + 1e-6f);
    pinv[r] = pv;
    float l[48];
    float mx = -INFINITY;
    #pragma unroll
    for (int t4 = 0; t4 < 12; t4++) {
        float4 a = {0.f,0.f,0.f,0.f};
        #pragma unroll
        for (int ks = 0; ks < NKS; ks++) {
            const float4 p = *(const float4*)&Rpart[((size_t)ks*NROW + r)*48 + t4*4];
            a.x += p.x; a.y += p.y; a.z += p.z; a.w += p.w;
        }
        f16x4 gh, gl;
        #pragma unroll
        for (int e = 0; e < 4; e++) {
            const float g = (&a.x)[e] * pv;             // G[m,t] = R*pinv
            const f16 hh = (f16)g;
            gh[e] = hh; gl[e] = (f16)(g - (float)hh);
            const int t = t4*4 + e;
            const float bias = mask[b*NT + t] ? 0.0f : NEGBIG;
            l[t] = g * SCALE + bias;                    // logit
            mx = fmaxf(mx, l[t]);
        }
        *(f16x4*)&Ghi[(size_t)r*64 + t4*4] = gh;
        *(f16x4*)&Glo[(size_t)r*64 + t4*4] = gl;
    }
    #pragma unroll
    for (int t4 = 0; t4 < 12; t4++) {
        float4 o;
        f16x4 wh, wlv;
        #pragma unroll
        for (int e = 0; e < 4; e++) {
            const float wv = expf(l[t4*4 + e] - mx);    // unnormalized
            (&o.x)[e] = wv;
            const f16 hh = (f16)wv;
            wh[e] = hh; wlv[e] = (f16)(wv - (float)hh);
        }
        *(float4*)&w[(size_t)r*48 + t4*4] = o;
        *(f16x4*)&Whi[(size_t)r*64 + t4*4] = wh;
        *(f16x4*)&Wlo[(size_t)r*64 + t4*4] = wlv;
    }
    const f16x4 z = {(f16)0.f, (f16)0.f, (f16)0.f, (f16)0.f};
    #pragma unroll
    for (int t4 = 12; t4 < 16; t4++) {       // K-pad 48..63
        *(f16x4*)&Whi[(size_t)r*64 + t4*4] = z;
        *(f16x4*)&Wlo[(size_t)r*64 + t4*4] = z;
        *(f16x4*)&Ghi[(size_t)r*64 + t4*4] = z;
        *(f16x4*)&Glo[(size_t)r*64 + t4*4] = z;
    }
}

// ---------------- kernel 4: score = W . G^T via MFMA; top-2+idx per 64-m tile ---------
__global__ __launch_bounds__(256) void k_scoreM(const f16* __restrict__ Whi,
                                                const f16* __restrict__ Wlo,
                                                const f16* __restrict__ Ghi,
                                                const f16* __restrict__ Glo,
                                                float4* __restrict__ part) {
    __shared__ float4 ent[4][64][17];            // 68 KB
    const int mt = blockIdx.x, rt = blockIdx.y, b = blockIdx.z;
    const int tid = threadIdx.x, wid = tid >> 6, lane = tid & 63;
    const int q15 = lane & 15, g4 = lane >> 4;
    const int wr = wid >> 1, wc = wid & 1;

    const size_t n0 = (size_t)(b*NN + rt*128 + wr*64);
    const size_t m0 = (size_t)(b*NN + mt*128 + wc*64);
    const int mbase = mt*128 + wc*64;

    f16x8 ah[4][2], al[4][2], bh[4][2], bl[4][2];
    #pragma unroll
    for (int i = 0; i < 4; i++)
        #pragma unroll
        for (int ksub = 0; ksub < 2; ksub++) {
            const size_t ao = (n0 + i*16 + q15)*64 + ksub*32 + g4*8;
            ah[i][ksub] = *(const f16x8*)&Whi[ao];
            al[i][ksub] = *(const f16x8*)&Wlo[ao];
            const size_t bo = (m0 + i*16 + q15)*64 + ksub*32 + g4*8;
            bh[i][ksub] = *(const f16x8*)&Ghi[bo];
            bl[i][ksub] = *(const f16x8*)&Glo[bo];
        }
    __builtin_amdgcn_sched_barrier(0);   // keep loads hoisted above all MFMAs

    f32x4 acc[4][4];
    #pragma unroll
    for (int i = 0; i < 4; i++)
        #pragma unroll
        for (int j = 0; j < 4; j++) acc[i][j] = (f32x4){0.f,0.f,0.f,0.f};

    #pragma unroll
    for (int ksub = 0; ksub < 2; ksub++)
        #pragma unroll
        for (int i = 0; i < 4; i++)
            #pragma unroll
            for (int j = 0; j < 4; j++) {
                acc[i][j] = __builtin_amdgcn_mfma_f32_16x16x32_f16(ah[i][ksub], bh[j][ksub], acc[i][j], 0, 0, 0);
                acc[i][j] = __builtin_amdgcn_mfma_f32_16x16x32_f16(al[i][ksub], bh[j][ksub], acc[i][j], 0, 0, 0);
                acc[i][j] = __builtin_amdgcn_mfma_f32_16x16x32_f16(ah[i][ksub], bl[j][ksub], acc[i][j], 0, 0, 0);
            }

    #pragma unroll
    for (int i = 0; i < 4; i++) {
        #pragma unroll
        for (int r = 0; r < 4; r++) {
            float v1 = -INFINITY, v2 = -INFINITY;
            int   i1 = 0x7FFFFFFF, i2 = 0x7FFFFFFF;
            #pragma unroll
            for (int j = 0; j < 4; j++) {
                const float s = acc[i][j][r];
                const int m = mbase + j*16 + q15;
                if (s > v1) { v2 = v1; i2 = i1; v1 = s; i1 = m; }
                else if (s > v2) { v2 = s; i2 = m; }
            }
            ent[wid][i*16 + g4*4 + r][q15] =
                make_float4(v1, __int_as_float(i1), v2, __int_as_float(i2));
        }
    }
    __syncthreads();
    {
        float V1 = -INFINITY, V2 = -INFINITY;
        int   I1 = 0x7FFFFFFF, I2 = 0x7FFFFFFF;
        #pragma unroll
        for (int q = 0; q < 16; q++) {
            const float4 e = ent[wid][lane][q];
            const float v1 = e.x, v2 = e.z;
            const int i1 = __float_as_int(e.y), i2 = __float_as_int(e.w);
            if (v1 > V1 || (v1 == V1 && i1 < I1)) {
                if (V1 > v2 || (V1 == v2 && I1 < i2)) { V2 = V1; I2 = I1; }
                else { V2 = v2; I2 = i2; }
                V1 = v1; I1 = i1;
            } else if (v1 > V2 || (v1 == V2 && i1 < I2)) { V2 = v1; I2 = i1; }
        }
        const size_t rowg = (size_t)b*NN + rt*128 + wr*64 + lane;
        part[rowg*12 + mt*2 + wc] =
            make_float4(V1, __int_as_float(I1), V2, __int_as_float(I2));
    }
}

// ---------------- kernel 5: fused merge + exact rescore + one-hot, RPB rows/block ----
__global__ __launch_bounds__(256) void k_final(const float* __restrict__ patches,
                                               const float* __restrict__ task_n,
                                               const float* __restrict__ w,
                                               const float* __restrict__ pinv,
                                               const float4* __restrict__ part,
                                               float* __restrict__ out) {
    __shared__ float qrow[ND];
    __shared__ float wl[48];
    __shared__ int   scand[24];
    __shared__ float swv[4];
    __shared__ int   swi[4];
    __shared__ int   s_idx, s_cnt;
    const int tid = threadIdx.x, wid = tid >> 6, lane = tid & 63;

    for (int rr = 0; rr < RPB; rr++) {
        const int row = blockIdx.x * RPB + rr;
        const int b = row / NN;
        __syncthreads();    // guard LDS reuse across row iterations
        if (wid == 0) {
            float myv = -INFINITY; int myi = 0x7FFFFFFF;
            if (lane < 24) {
                const float2 e = ((const float2*)part)[(size_t)row*24 + lane];
                myv = e.x; myi = __float_as_int(e.y);
            }
            float v = myv; int i = myi;
            #pragma unroll
            for (int off = 1; off <= 32; off <<= 1) {
                const float ov = __shfl_xor(v, off, 64);
                const int   oi = __shfl_xor(i, off, 64);
                if (ov > v || (ov == v && oi < i)) { v = ov; i = oi; }
            }
            const bool in_tau = (myv >= v - TAU);
            const unsigned long long mb  = __ballot(in_tau);
            const unsigned long long mbr = __ballot(in_tau && ((lane & 1) == 1));
            if (lane == 0) {
                s_idx = i;
                s_cnt = mbr ? 999 : __popcll(mb);   // tile's 2nd within TAU => full scan
            }
            if (in_tau && lane < 24) {
                const unsigned long long below = mb & ((lane == 0) ? 0ull : (~0ull >> (64 - lane)));
                scand[__popcll(below)] = myi;
            }
        }
        __syncthreads();
        const int cnt = s_cnt;
        if (cnt > 1) {
            if (tid < 12) *(float4*)&wl[tid*4] = *(const float4*)&w[(size_t)row*48 + tid*4];
            __syncthreads();
            {   // q = w . task_n (exact fp32, unnormalized w), cooperative
                float q[8] = {0.f,0.f,0.f,0.f,0.f,0.f,0.f,0.f};
                for (int t = 0; t < NT; t++) {
                    const float wt = wl[t];
                    const float* Tn = task_n + ((size_t)(b*NT + t))*ND + tid*8;
                    const float4 u0 = *(const float4*)Tn;
                    const float4 u1 = *(const float4*)(Tn + 4);
                    q[0] = fmaf(wt, u0.x, q[0]); q[1] = fmaf(wt, u0.y, q[1]);
                    q[2] = fmaf(wt, u0.z, q[2]); q[3] = fmaf(wt, u0.w, q[3]);
                    q[4] = fmaf(wt, u1.x, q[4]); q[5] = fmaf(wt, u1.y, q[5]);
                    q[6] = fmaf(wt, u1.z, q[6]); q[7] = fmaf(wt, u1.w, q[7]);
                }
                #pragma unroll
                for (int e2 = 0; e2 < 8; e2++) qrow[tid*8 + e2] = q[e2];
            }
            __syncthreads();
            float bw = -INFINITY; int bi = 0x7FFFFFFF;
            if (cnt != 999) {
                for (int c = wid; c < cnt; c += 4) {
                    const int m = scand[c];
                    const float* prow = patches + ((size_t)b*NN + m)*ND + lane*32;
                    const float* qp = qrow + lane*32;
                    float s = 0.f;
                    #pragma unroll
                    for (int k = 0; k < 8; k++) {
                        const float4 p = *(const float4*)(prow + k*4);
                        const float4 qv = *(const float4*)(qp + k*4);
                        s = fmaf(p.x, qv.x, s); s = fmaf(p.y, qv.y, s);
                        s = fmaf(p.z, qv.z, s); s = fmaf(p.w, qv.w, s);
                    }
                    #pragma unroll
                    for (int off = 32; off > 0; off >>= 1) s += __shfl_down(s, off, 64);
                    if (lane == 0) {
                        s *= pinv[b*NN + m];
                        if (s > bw || (s == bw && m < bi)) { bw = s; bi = m; }
                    }
                }
            } else {
                for (int m = wid; m < NN; m += 4) {
                    const float* prow = patches + ((size_t)b*NN + m)*ND + lane*32;
                    const float* qp = qrow + lane*32;
                    float s = 0.f;
                    #pragma unroll
                    for (int k = 0; k < 8; k++) {
                        const float4 p = *(const float4*)(prow + k*4);
                        const float4 qv = *(const float4*)(qp + k*4);
                        s = fmaf(p.x, qv.x, s); s = fmaf(p.y, qv.y, s);
                        s = fmaf(p.z, qv.z, s); s = fmaf(p.w, qv.w, s);
                    }
                    #pragma unroll
                    for (int off = 32; off > 0; off >>= 1) s += __shfl_down(s, off, 64);
                    if (lane == 0) {
                        s *= pinv[b*NN + m];
                        if (s > bw || (s == bw && m < bi)) { bw = s; bi = m; }
                    }
                }
            }
            if (lane == 0) { swv[wid] = bw; swi[wid] = bi; }
            __syncthreads();
            if (tid == 0) {
                float v = swv[0]; int i = swi[0];
                #pragma unroll
                for (int k = 1; k < 4; k++) {
                    if (swv[k] > v || (swv[k] == v && swi[k] < i)) { v = swv[k]; i = swi[k]; }
                }
                s_idx = i;
            }
            __syncthreads();
        }
        // one-hot write: 192 float4 per row
        const int m = s_idx;
        if (tid < 192) {
            float4 o = {0.f, 0.f, 0.f, 0.f};
            if ((m >> 2) == tid) ((float*)&o)[m & 3] = 1.0f;
            ((float4*)(out + (size_t)row*NN))[tid] = o;
        }
    }
}

// ---------------- launcher ----------------
extern "C" void kernel_launch(void* const* d_in, const int* in_sizes, int n_in,
                              void* d_out, int out_size, void* d_ws, size_t ws_size,
                              hipStream_t stream) {
    const float* patches = (const float*)d_in[0];
    const float* task    = (const float*)d_in[1];
    const int*   mask    = (const int*)d_in[2];
    float* out = (float*)d_out;

    char* p = (char*)d_ws;
    float* task_n  = (float*)p;  p += (size_t)NB*NT*ND*sizeof(float);      // 6.29 MB
    f16*   t_hi    = (f16*)p;    p += (size_t)NB*NT*ND*sizeof(f16);        // 3.15 MB
    f16*   t_lo    = (f16*)p;    p += (size_t)NB*NT*ND*sizeof(f16);        // 3.15 MB
    float* Rpart   = (float*)p;  p += (size_t)NKS*NROW*48*sizeof(float);   // 18.9 MB
    float* ssqpart = (float*)p;  p += (size_t)NKS*NROW*sizeof(float);      // 393 KB
    float* w       = (float*)p;  p += (size_t)NROW*48*sizeof(float);       // 2.36 MB
    float* pinv    = (float*)p;  p += (size_t)NROW*sizeof(float);          // 49 KB
    f16*   Whi     = (f16*)p;    p += (size_t)NROW*64*sizeof(f16);         // 1.57 MB
    f16*   Wlo     = (f16*)p;    p += (size_t)NROW*64*sizeof(f16);         // 1.57 MB
    f16*   Ghi     = (f16*)p;    p += (size_t)NROW*64*sizeof(f16);         // 1.57 MB
    f16*   Glo     = (f16*)p;    p += (size_t)NROW*64*sizeof(f16);         // 1.57 MB
    float4* part   = (float4*)p; p += (size_t)NROW*12*sizeof(float4);      // 2.36 MB

    k_prep_task<<<NB*NT, 256, 0, stream>>>(task, task_n, t_hi, t_lo);
    k_R<<<dim3(NN/64, NKS, NB), 256, 0, stream>>>(patches, t_hi, t_lo, Rpart, ssqpart);
    k_combine<<<NROW/256, 256, 0, stream>>>(Rpart, ssqpart, mask, w, pinv,
                                            Whi, Wlo, Ghi, Glo);
    k_scoreM<<<dim3(6, 6, NB), 256, 0, stream>>>(Whi, Wlo, Ghi, Glo, part);
    k_final<<<NROW/RPB, 256, 0, stream>>>(patches, task_n, w, pinv, part, out);
}

// Round 13
// 98.459 us; speedup vs baseline: 1.1647x; 1.1647x over previous
//
#include <hip/hip_runtime.h>
#include <math.h>

#define NB 16
#define NN 768
#define NT 48
#define ND 2048
#define NROW (NB*NN)                 // 12288
#define SCALE 0.02209708691207961f   // 1/sqrt(2048)
#define NEGBIG (-3.4028234663852886e38f)
#define TAU 2e-3f
#define KS 512                        // K-slice per ks-block in k_R
#define MSPLIT 16                     // m-chunks in k_scoreW
#define MCH (NN/MSPLIT)               // 48 m per chunk

typedef _Float16 f16;
typedef f16  f16x8 __attribute__((ext_vector_type(8)));
typedef f16  f16x4 __attribute__((ext_vector_type(4)));
typedef float f32x4 __attribute__((ext_vector_type(4)));

__device__ __forceinline__ void stage16(const void* g, void* l) {
    __builtin_amdgcn_global_load_lds(
        (const __attribute__((address_space(1))) unsigned int*)g,
        (__attribute__((address_space(3))) unsigned int*)l, 16, 0, 0);
}

// monotone top-4 insert: valid when calls use ascending index ni within a scan
// (tie => keep existing smaller index). value-only compares.
__device__ __forceinline__ void ins4m(float v[4], int idx[4], float nv, int ni) {
    const bool b0 = (v[0] >= nv);
    const bool b1 = (v[1] >= nv);
    const bool b2 = (v[2] >= nv);
    const bool b3 = (v[3] >= nv);
    const int pos = (int)b0 + (int)b1 + (int)b2 + (int)b3;
    if (pos <= 3) { if (pos == 3) { v[3] = nv; idx[3] = ni; } else { v[3] = v[2]; idx[3] = idx[2]; } }
    if (pos <= 2) { if (pos == 2) { v[2] = nv; idx[2] = ni; } else { v[2] = v[1]; idx[2] = idx[1]; } }
    if (pos <= 1) { if (pos == 1) { v[1] = nv; idx[1] = ni; } else { v[1] = v[0]; idx[1] = idx[0]; } }
    if (pos == 0) { v[0] = nv; idx[0] = ni; }
}

// ---------------- kernel 1: task rms-norm -> task_n fp32 + t_hi/t_lo f16 ----------------
__global__ __launch_bounds__(256) void k_prep_task(const float* __restrict__ task,
                                                   float* __restrict__ task_n,
                                                   f16* __restrict__ t_hi,
                                                   f16* __restrict__ t_lo) {
    __shared__ float sred[8];
    const int row = blockIdx.x;                 // b*NT + t
    const float4* src = (const float4*)(task + (size_t)row * ND);
    const int tid = threadIdx.x;
    float4 v0 = src[tid];
    float4 v1 = src[tid + 256];
    float s = v0.x*v0.x + v0.y*v0.y + v0.z*v0.z + v0.w*v0.w
            + v1.x*v1.x + v1.y*v1.y + v1.z*v1.z + v1.w*v1.w;
    #pragma unroll
    for (int off = 32; off > 0; off >>= 1) s += __shfl_down(s, off, 64);
    if ((tid & 63) == 0) sred[tid >> 6] = s;
    __syncthreads();
    if (tid == 0)
        sred[4] = 1.0f / sqrtf((sred[0]+sred[1]+sred[2]+sred[3]) * (1.0f/ND) + 1e-6f);
    __syncthreads();
    const float inv = sred[4];
    const size_t o = (size_t)row * ND;
    f16x4 h0, l0, h1, l1;
    float4 n0, n1;
    #pragma unroll
    for (int e = 0; e < 4; e++) {
        float f0 = (&v0.x)[e] * inv, f1 = (&v1.x)[e] * inv;
        (&n0.x)[e] = f0; (&n1.x)[e] = f1;
        f16 a = (f16)f0; h0[e] = a; l0[e] = (f16)(f0 - (float)a);
        f16 c = (f16)f1; h1[e] = c; l1[e] = (f16)(f1 - (float)c);
    }
    *(float4*)&task_n[o + tid*4]          = n0;
    *(float4*)&task_n[o + (tid+256)*4]    = n1;
    *(f16x4*)&t_hi[o + tid*4]             = h0;
    *(f16x4*)&t_lo[o + tid*4]             = l0;
    *(f16x4*)&t_hi[o + (tid+256)*4]       = h1;
    *(f16x4*)&t_lo[o + (tid+256)*4]       = l1;
}

// ---------------- kernel 2: R-partials + sumsq (streams patches once, pipelined) ------
// counted-vmcnt pipeline: B stage16 drained with vmcnt(4); A-prefetch (4 loads/wave)
// stays in flight across raw s_barrier + MFMA + next split.
__global__ __launch_bounds__(256) void k_R(const float* __restrict__ patches,
                                           const f16* __restrict__ t_hi,
                                           const f16* __restrict__ t_lo,
                                           float* __restrict__ Rpart,
                                           float* __restrict__ ssqpart) {
    __shared__ __align__(16) char Ah[64*128], Al[64*128];   // 8 KB each
    __shared__ __align__(16) char Bh[48*128], Bl[48*128];   // 6 KB each (28 KB total)
    const int rt = blockIdx.x, ks = blockIdx.y, b = blockIdx.z;
    const int tid = threadIdx.x, wid = tid >> 6, lane = tid & 63;
    const int q15 = lane & 15, g4 = lane >> 4;
    const int trow = tid >> 2, tq = tid & 3;   // A-load: row 0..63, quad pos
    const int lr = lane >> 3, lgch = (lane & 7) ^ lr;
    const int cxor = q15 & 7;

    const float* gP = patches + ((size_t)(b*NN + rt*64))*ND + ks*KS;
    const f16* gTh = t_hi + (size_t)b*NT*ND + ks*KS;
    const f16* gTl = t_lo + (size_t)b*NT*ND + ks*KS;

    f32x4 acc[3];
    #pragma unroll
    for (int j = 0; j < 3; j++) acc[j] = (f32x4){0.f,0.f,0.f,0.f};
    float ssq = 0.f;

    const float* aptr = gP + (size_t)trow*ND + tq*16;
    float4 va[4], vb[4];
    #pragma unroll
    for (int k = 0; k < 4; k++) va[k] = *(const float4*)(aptr + k*4);

    auto body = [&](float4 (&v)[4], float4 (&vn)[4], int kk, bool last) {
        // ---- stage B (tiny, L2-hot): issued FIRST so vmcnt(4) drains exactly these
        #pragma unroll
        for (int t2 = 0; t2 < 2; t2++) {
            const int u = wid + 4*t2;
            if (u < 6) {
                stage16(gTh + (size_t)(u*8 + lr)*ND + kk + lgch*8, Bh + u*1024);
                stage16(gTl + (size_t)(u*8 + lr)*ND + kk + lgch*8, Bl + u*1024);
            }
        }
        __builtin_amdgcn_sched_barrier(0);   // pin issue order: B before A
        // ---- prefetch next A tile (4 load instrs per wave, stay in flight)
        if (!last) {
            #pragma unroll
            for (int k = 0; k < 4; k++)
                vn[k] = *(const float4*)(aptr + kk + 64 + k*4);
        }
        __builtin_amdgcn_sched_barrier(0);
        // ---- split current A regs -> sumsq + f16 hi/lo -> swizzled LDS
        float lssq = 0.f;
        f16x8 hi8[2], lo8[2];
        #pragma unroll
        for (int k = 0; k < 4; k++)
            #pragma unroll
            for (int e = 0; e < 4; e++) {
                const float f = (&v[k].x)[e];
                lssq += f*f;
                const f16 h = (f16)f;
                hi8[k>>1][(k&1)*4 + e] = h;
                lo8[k>>1][(k&1)*4 + e] = (f16)(f - (float)h);
            }
        lssq += __shfl_xor(lssq, 1, 64);
        lssq += __shfl_xor(lssq, 2, 64);
        if (tq == 0) ssq += lssq;
        const int rb = trow * 128;
        #pragma unroll
        for (int c = 0; c < 2; c++) {
            const int ch = (2*tq + c) ^ (trow & 7);
            *(f16x8*)(Ah + rb + ch*16) = hi8[c];
            *(f16x8*)(Al + rb + ch*16) = lo8[c];
        }
        // ---- counted drain: B done, A prefetch still flying
        __builtin_amdgcn_sched_barrier(0);
        if (last) asm volatile("s_waitcnt vmcnt(0)" ::: "memory");
        else      asm volatile("s_waitcnt vmcnt(4)" ::: "memory");
        asm volatile("s_waitcnt lgkmcnt(0)" ::: "memory");
        __builtin_amdgcn_s_barrier();
        __builtin_amdgcn_sched_barrier(0);
        // ---- MFMA: 3 passes hi/lo over the 64-wide K-step
        #pragma unroll
        for (int ksub = 0; ksub < 2; ksub++) {
            const int chb = ((ksub*4 + g4) ^ cxor) << 4;
            const f16x8 a_h = *(const f16x8*)(Ah + (wid*16 + q15)*128 + chb);
            const f16x8 a_l = *(const f16x8*)(Al + (wid*16 + q15)*128 + chb);
            #pragma unroll
            for (int j = 0; j < 3; j++) {
                const f16x8 b_h = *(const f16x8*)(Bh + (j*16 + q15)*128 + chb);
                const f16x8 b_l = *(const f16x8*)(Bl + (j*16 + q15)*128 + chb);
                acc[j] = __builtin_amdgcn_mfma_f32_16x16x32_f16(a_h, b_h, acc[j], 0, 0, 0);
                acc[j] = __builtin_amdgcn_mfma_f32_16x16x32_f16(a_l, b_h, acc[j], 0, 0, 0);
                acc[j] = __builtin_amdgcn_mfma_f32_16x16x32_f16(a_h, b_l, acc[j], 0, 0, 0);
            }
        }
        // raw barrier (LDS reads already consumed into regs before MFMA issue)
        asm volatile("" ::: "memory");
        __builtin_amdgcn_s_barrier();
        __builtin_amdgcn_sched_barrier(0);
    };

    // KS/64 = 8 steps, statically paired (double v-register buffer, rule #20)
    body(va, vb,   0, false);
    body(vb, va,  64, false);
    body(va, vb, 128, false);
    body(vb, va, 192, false);
    body(va, vb, 256, false);
    body(vb, va, 320, false);
    body(va, vb, 384, false);
    body(vb, va, 448, true);

    const int grow = b*NN + rt*64;
    #pragma unroll
    for (int j = 0; j < 3; j++)
        #pragma unroll
        for (int r = 0; r < 4; r++)
            Rpart[((size_t)ks*NROW + grow + wid*16 + g4*4 + r)*48 + j*16 + q15] = acc[j][r];
    if (tq == 0)
        ssqpart[(size_t)ks*NROW + grow + trow] = ssq;
}

// ---------------- kernel 3: combine partials -> pinv, R, w(softmax) ----------------
__global__ __launch_bounds__(256) void k_combine(const float* __restrict__ Rpart,
                                                 const float* __restrict__ ssqpart,
                                                 const int* __restrict__ mask,
                                                 float* __restrict__ R,
                                                 float* __restrict__ w,
                                                 float* __restrict__ pinv) {
    const int r = blockIdx.x * 256 + threadIdx.x;   // 0..12287
    const int b = r / NN;
    float ss = 0.f;
    #pragma unroll
    for (int ks = 0; ks < 4; ks++) ss += ssqpart[(size_t)ks*NROW + r];
    const float pv = 1.0f / sqrtf(ss * (1.0f/ND) + 1e-6f);
    pinv[r] = pv;
    float l[48];
    float mx = -INFINITY;
    #pragma unroll
    for (int t4 = 0; t4 < 12; t4++) {
        float4 a = {0.f,0.f,0.f,0.f};
        #pragma unroll
        for (int ks = 0; ks < 4; ks++) {
            const float4 p = *(const float4*)&Rpart[((size_t)ks*NROW + r)*48 + t4*4];
            a.x += p.x; a.y += p.y; a.z += p.z; a.w += p.w;
        }
        *(float4*)&R[(size_t)r*48 + t4*4] = a;
        #pragma unroll
        for (int e = 0; e < 4; e++) {
            const int t = t4*4 + e;
            const float bias = mask[b*NT + t] ? 0.0f : NEGBIG;
            l[t] = (&a.x)[e] * pv * SCALE + bias;
            mx = fmaxf(mx, l[t]);
        }
    }
    float sum = 0.f;
    #pragma unroll
    for (int t = 0; t < 48; t++) { l[t] = expf(l[t] - mx); sum += l[t]; }
    const float inv = 1.0f / sum;
    #pragma unroll
    for (int t4 = 0; t4 < 12; t4++) {
        float4 o;
        #pragma unroll
        for (int e = 0; e < 4; e++) (&o.x)[e] = l[t4*4 + e] * inv;
        *(float4*)&w[(size_t)r*48 + t4*4] = o;
    }
}

// ---------------- kernel 4: score = pinv[m]*(W.R^T), gated top-4, ILP-4 ---------
__global__ __launch_bounds__(256) void k_scoreW(const float* __restrict__ w,
                                                const float* __restrict__ R,
                                                const float* __restrict__ pinv,
                                                float4* __restrict__ part) {
    __shared__ float Rl[MCH*48];
    __shared__ float pl[MCH];
    const int rt = blockIdx.x, ms = blockIdx.y;
    const int tid = threadIdx.x;
    const int row = rt*256 + tid;
    const int b = row / NN;                 // constant per block (256 | 768)
    const int m0g = b*NN + ms*MCH;
    for (int u = tid; u < MCH*12; u += 256) {
        const int m = u / 12, t4 = u % 12;
        *(float4*)&Rl[m*48 + t4*4] = *(const float4*)&R[((size_t)(m0g + m))*48 + t4*4];
    }
    if (tid < MCH) pl[tid] = pinv[m0g + tid];
    __syncthreads();
    float4 wr[12];
    #pragma unroll
    for (int t4 = 0; t4 < 12; t4++)
        wr[t4] = *(const float4*)&w[(size_t)row*48 + t4*4];
    float tv[4] = {-INFINITY, -INFINITY, -INFINITY, -INFINITY};
    int   ti[4] = {0x7FFFFFFF, 0x7FFFFFFF, 0x7FFFFFFF, 0x7FFFFFFF};
    #pragma unroll 2
    for (int m = 0; m < MCH; m += 4) {
        float s0 = 0.f, s1 = 0.f, s2 = 0.f, s3 = 0.f;
        #pragma unroll
        for (int t4 = 0; t4 < 12; t4++) {
            const float4 r0 = *(const float4*)&Rl[(m+0)*48 + t4*4];
            const float4 r1 = *(const float4*)&Rl[(m+1)*48 + t4*4];
            const float4 r2 = *(const float4*)&Rl[(m+2)*48 + t4*4];
            const float4 r3 = *(const float4*)&Rl[(m+3)*48 + t4*4];
            const float4 wv = wr[t4];
            s0 = fmaf(wv.x, r0.x, s0); s1 = fmaf(wv.x, r1.x, s1);
            s2 = fmaf(wv.x, r2.x, s2); s3 = fmaf(wv.x, r3.x, s3);
            s0 = fmaf(wv.y, r0.y, s0); s1 = fmaf(wv.y, r1.y, s1);
            s2 = fmaf(wv.y, r2.y, s2); s3 = fmaf(wv.y, r3.y, s3);
            s0 = fmaf(wv.z, r0.z, s0); s1 = fmaf(wv.z, r1.z, s1);
            s2 = fmaf(wv.z, r2.z, s2); s3 = fmaf(wv.z, r3.z, s3);
            s0 = fmaf(wv.w, r0.w, s0); s1 = fmaf(wv.w, r1.w, s1);
            s2 = fmaf(wv.w, r2.w, s2); s3 = fmaf(wv.w, r3.w, s3);
        }
        s0 *= pl[m+0]; s1 *= pl[m+1]; s2 *= pl[m+2]; s3 *= pl[m+3];
        // gate: only touch the top-4 if this group can enter it
        const float gm = fmaxf(fmaxf(s0, s1), fmaxf(s2, s3));
        if (gm >= tv[3]) {
            const int mg = ms*MCH + m;
            ins4m(tv, ti, s0, mg+0);
            ins4m(tv, ti, s1, mg+1);
            ins4m(tv, ti, s2, mg+2);
            ins4m(tv, ti, s3, mg+3);
        }
    }
    part[((size_t)row*MSPLIT + ms)*2]     = make_float4(tv[0], __int_as_float(ti[0]), tv[1], __int_as_float(ti[1]));
    part[((size_t)row*MSPLIT + ms)*2 + 1] = make_float4(tv[2], __int_as_float(ti[2]), tv[3], __int_as_float(ti[3]));
}

// ---------------- kernel 5: fused merge + exact rescore + one-hot write ----------
__global__ __launch_bounds__(256) void k_final(const float* __restrict__ patches,
                                               const float* __restrict__ task_n,
                                               const float* __restrict__ w,
                                               const float* __restrict__ pinv,
                                               const float4* __restrict__ part,
                                               float* __restrict__ out) {
    __shared__ float qrow[ND];
    __shared__ float wl[48];
    __shared__ int   scand[64];
    __shared__ float swv[4];
    __shared__ int   swi[4];
    __shared__ int   s_idx, s_cnt;
    const int row = blockIdx.x;
    const int b = row / NN;
    const int tid = threadIdx.x, wid = tid >> 6, lane = tid & 63;

    if (wid == 0) {
        // lane l holds candidate l: chunk l>>2, rank l&3
        const float2 e = ((const float2*)part)[(size_t)row*64 + lane];
        const float myv = e.x;
        const int   myi = __float_as_int(e.y);
        float v = myv; int i = myi;
        #pragma unroll
        for (int off = 1; off <= 32; off <<= 1) {
            const float ov = __shfl_xor(v, off, 64);
            const int   oi = __shfl_xor(i, off, 64);
            if (ov > v || (ov == v && oi < i)) { v = ov; i = oi; }
        }
        const bool in_tau = (myv >= v - TAU);
        const unsigned long long mb  = __ballot(in_tau);
        const unsigned long long mb4 = __ballot(in_tau && ((lane & 3) == 3));
        if (lane == 0) {
            s_idx = i;
            s_cnt = mb4 ? 999 : __popcll(mb);   // chunk 4th within TAU => full scan
        }
        if (in_tau) {
            const unsigned long long below = mb & ((lane == 0) ? 0ull : (~0ull >> (64 - lane)));
            scand[__popcll(below)] = myi;
        }
    }
    __syncthreads();
    const int cnt = s_cnt;
    if (cnt > 1) {
        if (tid < 12) *(float4*)&wl[tid*4] = *(const float4*)&w[(size_t)row*48 + tid*4];
        __syncthreads();
        {   // q = w . task_n (exact fp32), cooperative: thread owns 8 floats
            float q[8] = {0.f,0.f,0.f,0.f,0.f,0.f,0.f,0.f};
            for (int t = 0; t < NT; t++) {
                const float wt = wl[t];
                const float* Tn = task_n + ((size_t)(b*NT + t))*ND + tid*8;
                const float4 u0 = *(const float4*)Tn;
                const float4 u1 = *(const float4*)(Tn + 4);
                q[0] = fmaf(wt, u0.x, q[0]); q[1] = fmaf(wt, u0.y, q[1]);
                q[2] = fmaf(wt, u0.z, q[2]); q[3] = fmaf(wt, u0.w, q[3]);
                q[4] = fmaf(wt, u1.x, q[4]); q[5] = fmaf(wt, u1.y, q[5]);
                q[6] = fmaf(wt, u1.z, q[6]); q[7] = fmaf(wt, u1.w, q[7]);
            }
            #pragma unroll
            for (int e2 = 0; e2 < 8; e2++) qrow[tid*8 + e2] = q[e2];
        }
        __syncthreads();
        float bw = -INFINITY; int bi = 0x7FFFFFFF;
        if (cnt != 999) {
            for (int c = wid; c < cnt; c += 4) {
                const int m = scand[c];
                const float* prow = patches + ((size_t)b*NN + m)*ND + lane*32;
                const float* qp = qrow + lane*32;
                float s = 0.f;
                #pragma unroll
                for (int k = 0; k < 8; k++) {
                    const float4 p = *(const float4*)(prow + k*4);
                    const float4 qv = *(const float4*)(qp + k*4);
                    s = fmaf(p.x, qv.x, s); s = fmaf(p.y, qv.y, s);
                    s = fmaf(p.z, qv.z, s); s = fmaf(p.w, qv.w, s);
                }
                #pragma unroll
                for (int off = 32; off > 0; off >>= 1) s += __shfl_down(s, off, 64);
                if (lane == 0) {
                    s *= pinv[b*NN + m];
                    if (s > bw || (s == bw && m < bi)) { bw = s; bi = m; }
                }
            }
        } else {
            for (int m = wid; m < NN; m += 4) {
                const float* prow = patches + ((size_t)b*NN + m)*ND + lane*32;
                const float* qp = qrow + lane*32;
                float s = 0.f;
                #pragma unroll
                for (int k = 0; k < 8; k++) {
                    const float4 p = *(const float4*)(prow + k*4);
                    const float4 qv = *(const float4*)(qp + k*4);
                    s = fmaf(p.x, qv.x, s); s = fmaf(p.y, qv.y, s);
                    s = fmaf(p.z, qv.z, s); s = fmaf(p.w, qv.w, s);
                }
                #pragma unroll
                for (int off = 32; off > 0; off >>= 1) s += __shfl_down(s, off, 64);
                if (lane == 0) {
                    s *= pinv[b*NN + m];
                    if (s > bw || (s == bw && m < bi)) { bw = s; bi = m; }
                }
            }
        }
        if (lane == 0) { swv[wid] = bw; swi[wid] = bi; }
        __syncthreads();
        if (tid == 0) {
            float v = swv[0]; int i = swi[0];
            #pragma unroll
            for (int k = 1; k < 4; k++) {
                if (swv[k] > v || (swv[k] == v && swi[k] < i)) { v = swv[k]; i = swi[k]; }
            }
            s_idx = i;
        }
        __syncthreads();
    }
    // one-hot write: 192 float4 per row
    const int m = s_idx;
    if (tid < 192) {
        float4 o = {0.f, 0.f, 0.f, 0.f};
        if ((m >> 2) == tid) ((float*)&o)[m & 3] = 1.0f;
        ((float4*)(out + (size_t)row*NN))[tid] = o;
    }
}

// ---------------- launcher ----------------
extern "C" void kernel_launch(void* const* d_in, const int* in_sizes, int n_in,
                              void* d_out, int out_size, void* d_ws, size_t ws_size,
                              hipStream_t stream) {
    const float* patches = (const float*)d_in[0];
    const float* task    = (const float*)d_in[1];
    const int*   mask    = (const int*)d_in[2];
    float* out = (float*)d_out;

    char* p = (char*)d_ws;
    float* task_n  = (float*)p;  p += (size_t)NB*NT*ND*sizeof(float);    // 6.29 MB
    f16*   t_hi    = (f16*)p;    p += (size_t)NB*NT*ND*sizeof(f16);      // 3.15 MB
    f16*   t_lo    = (f16*)p;    p += (size_t)NB*NT*ND*sizeof(f16);      // 3.15 MB
    float* Rpart   = (float*)p;  p += (size_t)4*NROW*48*sizeof(float);   // 9.44 MB
    float* ssqpart = (float*)p;  p += (size_t)4*NROW*sizeof(float);      // 197 KB
    float* R       = (float*)p;  p += (size_t)NROW*48*sizeof(float);     // 2.36 MB
    float* w       = (float*)p;  p += (size_t)NROW*48*sizeof(float);     // 2.36 MB
    float* pinv    = (float*)p;  p += (size_t)NROW*sizeof(float);        // 49 KB
    float4* part   = (float4*)p; p += (size_t)NROW*MSPLIT*2*sizeof(float4); // 6.3 MB

    k_prep_task<<<NB*NT, 256, 0, stream>>>(task, task_n, t_hi, t_lo);
    k_R<<<dim3(NN/64, 4, NB), 256, 0, stream>>>(patches, t_hi, t_lo, Rpart, ssqpart);
    k_combine<<<NROW/256, 256, 0, stream>>>(Rpart, ssqpart, mask, R, w, pinv);
    k_scoreW<<<dim3(NROW/256, MSPLIT), 256, 0, stream>>>(w, R, pinv, part);
    k_final<<<NROW, 256, 0, stream>>>(patches, task_n, w, pinv, part, out);
}